// Round 1
// baseline (928.692 us; speedup 1.0000x reference)
//
#include <hip/hip_runtime.h>
#include <hip/hip_bf16.h>

#define EPSBN 1e-5f

// ---------------- init: zero counters / accumulators ----------------
__global__ void init_kernel(int* __restrict__ deg, int* __restrict__ cursor,
                            float* __restrict__ sums, float* __restrict__ cnt,
                            int* __restrict__ counter, int n, int g) {
    int i = blockIdx.x * 256 + threadIdx.x;
    if (i < n) { deg[i] = 0; cursor[i] = 0; }
    if (i < g * 128) sums[i] = 0.f;
    if (i < g) cnt[i] = 0.f;
    if (i == 0) *counter = 0;
}

// ---------------- degree count ----------------
__global__ void count_kernel(const int* __restrict__ dst, int* __restrict__ deg, int e) {
    int i = blockIdx.x * 256 + threadIdx.x;
    if (i < e) atomicAdd(&deg[dst[i]], 1);
}

// ---------------- dinv = rsqrt(deg + 1) ----------------
__global__ void dinv_kernel(const int* __restrict__ deg, float* __restrict__ dinv, int n) {
    int i = blockIdx.x * 256 + threadIdx.x;
    if (i < n) dinv[i] = rsqrtf((float)deg[i] + 1.0f);
}

// ---------------- reserve CSR ranges (wave-aggregated atomic, no scan) ----------------
__global__ void reserve_kernel(const int* __restrict__ deg, int* __restrict__ offs,
                               int* __restrict__ counter, int n) {
    int i = blockIdx.x * 256 + threadIdx.x;
    int lane = threadIdx.x & 63;
    int d = (i < n) ? deg[i] : 0;
    int scan = d;
    #pragma unroll
    for (int o = 1; o < 64; o <<= 1) {
        int v = __shfl_up(scan, o);
        if (lane >= o) scan += v;
    }
    int total = __shfl(scan, 63);
    int base = 0;
    if (lane == 63) base = atomicAdd(counter, total);
    base = __shfl(base, 63);
    if (i < n) offs[i] = base + scan - d;  // exclusive within wave
}

// ---------------- fill CSR ----------------
__global__ void fill_kernel(const int* __restrict__ src, const int* __restrict__ dst,
                            const int* __restrict__ offs, int* __restrict__ cursor,
                            const float* __restrict__ dinv,
                            int* __restrict__ csr_src, float* __restrict__ csr_norm, int e) {
    int i = blockIdx.x * 256 + threadIdx.x;
    if (i >= e) return;
    int s = src[i], d = dst[i];
    int p = atomicAdd(&cursor[d], 1);
    int j = offs[d] + p;
    csr_src[j] = s;
    csr_norm[j] = dinv[s] * dinv[d];
}

// ---------------- layer-0 GEMM: [N,7] @ [7,128] ----------------
__global__ void gemm7(const float* __restrict__ x, const float* __restrict__ W,
                      float* __restrict__ out, int n) {
    __shared__ float sW[7 * 128];
    int t = threadIdx.x;
    for (int i = t; i < 7 * 128; i += 256) sW[i] = W[i];
    __syncthreads();
    int idx = blockIdx.x * 256 + t;
    int row = idx >> 7, f = idx & 127;
    if (row < n) {
        const float* xr = x + (size_t)row * 7;
        float acc = 0.f;
        #pragma unroll
        for (int k = 0; k < 7; ++k) acc += xr[k] * sW[k * 128 + f];
        out[idx] = acc;
    }
}

// ---------------- 128x128 GEMM, 64-row tiles, 4x8 register tile ----------------
__launch_bounds__(256)
__global__ void gemm128(const float* __restrict__ h, const float* __restrict__ W,
                        float* __restrict__ out, int n) {
    __shared__ float sh[64 * 132];   // [row][k], +4 pad
    int t = threadIdx.x;
    int row0 = blockIdx.x * 64;
    int rows = n - row0; if (rows > 64) rows = 64;

    for (int idx4 = t * 4; idx4 < 64 * 128; idx4 += 1024) {
        int r = idx4 >> 7, k = idx4 & 127;
        float4 v;
        if (r < rows) v = *(const float4*)(h + (size_t)(row0 + r) * 128 + k);
        else          v = make_float4(0.f, 0.f, 0.f, 0.f);
        *(float4*)(&sh[r * 132 + k]) = v;
    }
    __syncthreads();

    int f0 = (t & 15) * 8;
    int r0 = (t >> 4) * 4;
    float acc[4][8];
    #pragma unroll
    for (int i = 0; i < 4; ++i)
        #pragma unroll
        for (int c = 0; c < 8; ++c) acc[i][c] = 0.f;

    for (int k0 = 0; k0 < 128; k0 += 4) {
        float a_s[4][4];
        #pragma unroll
        for (int i = 0; i < 4; ++i) {
            float4 v = *(const float4*)(&sh[(r0 + i) * 132 + k0]);
            a_s[i][0] = v.x; a_s[i][1] = v.y; a_s[i][2] = v.z; a_s[i][3] = v.w;
        }
        float w_s[4][8];
        #pragma unroll
        for (int j = 0; j < 4; ++j) {
            float4 w0 = *(const float4*)(W + (size_t)(k0 + j) * 128 + f0);
            float4 w1 = *(const float4*)(W + (size_t)(k0 + j) * 128 + f0 + 4);
            w_s[j][0] = w0.x; w_s[j][1] = w0.y; w_s[j][2] = w0.z; w_s[j][3] = w0.w;
            w_s[j][4] = w1.x; w_s[j][5] = w1.y; w_s[j][6] = w1.z; w_s[j][7] = w1.w;
        }
        #pragma unroll
        for (int j = 0; j < 4; ++j)
            #pragma unroll
            for (int i = 0; i < 4; ++i)
                #pragma unroll
                for (int c = 0; c < 8; ++c)
                    acc[i][c] = fmaf(a_s[i][j], w_s[j][c], acc[i][c]);
    }

    #pragma unroll
    for (int i = 0; i < 4; ++i) {
        if (r0 + i < rows) {
            float* op = out + (size_t)(row0 + r0 + i) * 128 + f0;
            float4 o0 = make_float4(acc[i][0], acc[i][1], acc[i][2], acc[i][3]);
            float4 o1 = make_float4(acc[i][4], acc[i][5], acc[i][6], acc[i][7]);
            *(float4*)op = o0;
            *(float4*)(op + 4) = o1;
        }
    }
}

// ---------------- aggregation + bias + BN + ReLU (wave per node) ----------------
__global__ void agg_bn_relu(const float* __restrict__ hW, const int* __restrict__ csr_src,
                            const float* __restrict__ csr_norm, const int* __restrict__ offs,
                            const int* __restrict__ degi, const float* __restrict__ dinv,
                            const float* __restrict__ bias, const float* __restrict__ gamma,
                            const float* __restrict__ beta, const float* __restrict__ mean,
                            const float* __restrict__ var, float* __restrict__ out, int n) {
    int lane = threadIdx.x & 63;
    int node = blockIdx.x * 4 + (threadIdx.x >> 6);
    if (node >= n) return;
    float di = dinv[node];
    size_t base = (size_t)node * 128;
    float acc0 = di * di * hW[base + lane];
    float acc1 = di * di * hW[base + 64 + lane];
    int off = offs[node], cnt = degi[node];
    for (int b0 = 0; b0 < cnt; b0 += 64) {
        int j = b0 + lane;
        int s = 0; float nm = 0.f;
        if (j < cnt) { s = csr_src[off + j]; nm = csr_norm[off + j]; }
        int m = cnt - b0; if (m > 64) m = 64;
        for (int e = 0; e < m; ++e) {
            int ss = __shfl(s, e);
            float nn = __shfl(nm, e);
            const float* hr = hW + (size_t)ss * 128;
            acc0 = fmaf(nn, hr[lane], acc0);
            acc1 = fmaf(nn, hr[64 + lane], acc1);
        }
    }
    float s0 = gamma[lane] * rsqrtf(var[lane] + EPSBN);
    float s1 = gamma[64 + lane] * rsqrtf(var[64 + lane] + EPSBN);
    float o0 = fmaf(s0, acc0 + bias[lane] - mean[lane], beta[lane]);
    float o1 = fmaf(s1, acc1 + bias[64 + lane] - mean[64 + lane], beta[64 + lane]);
    out[base + lane] = fmaxf(o0, 0.f);
    out[base + 64 + lane] = fmaxf(o1, 0.f);
}

// ---------------- global mean pool (sums via atomics) ----------------
__global__ void pool_kernel(const float* __restrict__ h, const int* __restrict__ batch,
                            float* __restrict__ sums, float* __restrict__ cnt, int n) {
    int lane = threadIdx.x & 63;
    int node = blockIdx.x * 4 + (threadIdx.x >> 6);
    if (node >= n) return;
    int g = batch[node];
    size_t base = (size_t)node * 128;
    atomicAdd(&sums[(size_t)g * 128 + lane], h[base + lane]);
    atomicAdd(&sums[(size_t)g * 128 + 64 + lane], h[base + 64 + lane]);
    if (lane == 0) atomicAdd(&cnt[g], 1.0f);
}

// ---------------- pocket MLP: 28->64 relu ->64 ----------------
__global__ void pk_kernel(const float* __restrict__ pf, const float* __restrict__ W1,
                          const float* __restrict__ b1, const float* __restrict__ W2,
                          const float* __restrict__ b2, float* __restrict__ pk) {
    __shared__ float h1[64];
    int t = threadIdx.x;
    float acc = b1[t];
    #pragma unroll
    for (int k = 0; k < 28; ++k) acc = fmaf(pf[k], W1[k * 64 + t], acc);
    h1[t] = fmaxf(acc, 0.f);
    __syncthreads();
    float acc2 = b2[t];
    for (int k = 0; k < 64; ++k) acc2 = fmaf(h1[k], W2[k * 64 + t], acc2);
    pk[t] = acc2;
}

// ---------------- fold bilinear: M[o,i] = sum_j bilW[o,i,j] * pk[j] ----------------
__global__ void bilM_kernel(const float* __restrict__ bilW, const float* __restrict__ pk,
                            float* __restrict__ M) {
    __shared__ float spk[64];
    int t = threadIdx.x;
    if (t < 64) spk[t] = pk[t];
    __syncthreads();
    int idx = blockIdx.x * 256 + t;   // o*128 + i, total 8192
    if (idx < 64 * 128) {
        const float* wr = bilW + (size_t)idx * 64;
        float acc = 0.f;
        #pragma unroll 8
        for (int j = 0; j < 64; ++j) acc = fmaf(wr[j], spk[j], acc);
        M[idx] = acc;
    }
}

// ---------------- per-graph tail: ligand -> bilinear -> classifier ----------------
__global__ void final_kernel(const float* __restrict__ sums, const float* __restrict__ cnt,
                             const float* __restrict__ M, const float* __restrict__ bil_b,
                             const float* __restrict__ cW1, const float* __restrict__ cb1,
                             const float* __restrict__ cW2, const float* __restrict__ cb2,
                             float* __restrict__ out) {
    __shared__ float lig[128];
    __shared__ float inter[64];
    __shared__ float hc[32];
    int g = blockIdx.x, t = threadIdx.x;
    float c = fmaxf(cnt[g], 1.0f);
    lig[t] = sums[(size_t)g * 128 + t] / c;
    __syncthreads();
    if (t < 64) {
        float acc = bil_b[t];
        const float* mr = M + (size_t)t * 128;
        #pragma unroll 8
        for (int i = 0; i < 128; ++i) acc = fmaf(lig[i], mr[i], acc);
        inter[t] = acc;
    }
    __syncthreads();
    if (t < 32) {
        float acc = cb1[t];
        #pragma unroll 8
        for (int o = 0; o < 64; ++o) acc = fmaf(inter[o], cW1[o * 32 + t], acc);
        hc[t] = fmaxf(acc, 0.f);
    }
    __syncthreads();
    if (t == 0) {
        float acc = cb2[0];
        #pragma unroll
        for (int j = 0; j < 32; ++j) acc = fmaf(hc[j], cW2[j], acc);
        out[g] = acc;
    }
}

extern "C" void kernel_launch(void* const* d_in, const int* in_sizes, int n_in,
                              void* d_out, int out_size, void* d_ws, size_t ws_size,
                              hipStream_t stream) {
    const float* x        = (const float*)d_in[0];
    const int*   edge     = (const int*)d_in[1];
    const int*   batch    = (const int*)d_in[2];
    const float* pocket   = (const float*)d_in[3];
    const float* conv0_W  = (const float*)d_in[4];
    const float* conv0_b  = (const float*)d_in[5];
    const float* convs_W  = (const float*)d_in[6];
    const float* convs_b  = (const float*)d_in[7];
    const float* bn_gamma = (const float*)d_in[8];
    const float* bn_beta  = (const float*)d_in[9];
    const float* bn_mean  = (const float*)d_in[10];
    const float* bn_var   = (const float*)d_in[11];
    const float* pmlp_W1  = (const float*)d_in[12];
    const float* pmlp_b1  = (const float*)d_in[13];
    const float* pmlp_W2  = (const float*)d_in[14];
    const float* pmlp_b2  = (const float*)d_in[15];
    const float* bil_W    = (const float*)d_in[16];
    const float* bil_b    = (const float*)d_in[17];
    const float* cls_W1   = (const float*)d_in[18];
    const float* cls_b1   = (const float*)d_in[19];
    const float* cls_W2   = (const float*)d_in[20];
    const float* cls_b2   = (const float*)d_in[21];

    const int N = in_sizes[0] / 7;
    const int E = in_sizes[1] / 2;
    const int G = out_size;
    const int* srcA = edge;
    const int* dstA = edge + E;

    char* p = (char*)d_ws;
    auto alloc = [&](size_t bytes) -> void* {
        void* r = (void*)p;
        p += (bytes + 255) & ~(size_t)255;
        return r;
    };
    int*   deg      = (int*)alloc((size_t)N * 4);
    int*   cursor   = (int*)alloc((size_t)N * 4);
    int*   offs     = (int*)alloc((size_t)N * 4);
    int*   counter  = (int*)alloc(256);
    float* dinv     = (float*)alloc((size_t)N * 4);
    int*   csr_src  = (int*)alloc((size_t)E * 4);
    float* csr_norm = (float*)alloc((size_t)E * 4);
    float* bufA     = (float*)alloc((size_t)N * 128 * 4);
    float* bufB     = (float*)alloc((size_t)N * 128 * 4);
    float* sums     = (float*)alloc((size_t)G * 128 * 4);
    float* cntf     = (float*)alloc((size_t)G * 4);
    float* pk       = (float*)alloc(64 * 4);
    float* M        = (float*)alloc(64 * 128 * 4);

    int initN = N > G * 128 ? N : G * 128;
    init_kernel<<<(initN + 255) / 256, 256, 0, stream>>>(deg, cursor, sums, cntf, counter, N, G);
    count_kernel<<<(E + 255) / 256, 256, 0, stream>>>(dstA, deg, E);
    dinv_kernel<<<(N + 255) / 256, 256, 0, stream>>>(deg, dinv, N);
    reserve_kernel<<<(N + 255) / 256, 256, 0, stream>>>(deg, offs, counter, N);
    fill_kernel<<<(E + 255) / 256, 256, 0, stream>>>(srcA, dstA, offs, cursor, dinv,
                                                     csr_src, csr_norm, E);

    // layer 0
    gemm7<<<((size_t)N * 128 + 255) / 256, 256, 0, stream>>>(x, conv0_W, bufA, N);
    agg_bn_relu<<<(N + 3) / 4, 256, 0, stream>>>(bufA, csr_src, csr_norm, offs, deg, dinv,
                                                 conv0_b, bn_gamma, bn_beta, bn_mean, bn_var,
                                                 bufB, N);
    // layer 1
    gemm128<<<(N + 63) / 64, 256, 0, stream>>>(bufB, convs_W, bufA, N);
    agg_bn_relu<<<(N + 3) / 4, 256, 0, stream>>>(bufA, csr_src, csr_norm, offs, deg, dinv,
                                                 convs_b, bn_gamma + 128, bn_beta + 128,
                                                 bn_mean + 128, bn_var + 128, bufB, N);
    // layer 2
    gemm128<<<(N + 63) / 64, 256, 0, stream>>>(bufB, convs_W + 128 * 128, bufA, N);
    agg_bn_relu<<<(N + 3) / 4, 256, 0, stream>>>(bufA, csr_src, csr_norm, offs, deg, dinv,
                                                 convs_b + 128, bn_gamma + 256, bn_beta + 256,
                                                 bn_mean + 256, bn_var + 256, bufB, N);

    pool_kernel<<<(N + 3) / 4, 256, 0, stream>>>(bufB, batch, sums, cntf, N);
    pk_kernel<<<1, 64, 0, stream>>>(pocket, pmlp_W1, pmlp_b1, pmlp_W2, pmlp_b2, pk);
    bilM_kernel<<<32, 256, 0, stream>>>(bil_W, pk, M);
    final_kernel<<<G, 128, 0, stream>>>(sums, cntf, M, bil_b, cls_W1, cls_b1, cls_W2, cls_b2,
                                        (float*)d_out);
}

// Round 2
// 721.532 us; speedup vs baseline: 1.2871x; 1.2871x over previous
//
#include <hip/hip_runtime.h>
#include <hip/hip_bf16.h>

#define EPSBN 1e-5f

// ---------------- init: zero counters ----------------
__global__ void init_kernel(int* __restrict__ deg, int* __restrict__ cursor,
                            int* __restrict__ counter, int n) {
    int i = blockIdx.x * 256 + threadIdx.x;
    if (i < n) { deg[i] = 0; cursor[i] = 0; }
    if (i == 0) *counter = 0;
}

// ---------------- degree count ----------------
__global__ void count_kernel(const int* __restrict__ dst, int* __restrict__ deg, int e) {
    int i = blockIdx.x * 256 + threadIdx.x;
    if (i < e) atomicAdd(&deg[dst[i]], 1);
}

// ---------------- dinv = rsqrt(deg + 1) ----------------
__global__ void dinv_kernel(const int* __restrict__ deg, float* __restrict__ dinv, int n) {
    int i = blockIdx.x * 256 + threadIdx.x;
    if (i < n) dinv[i] = rsqrtf((float)deg[i] + 1.0f);
}

// ---------------- reserve CSR ranges (wave-aggregated atomic) ----------------
__global__ void reserve_kernel(const int* __restrict__ deg, int* __restrict__ offs,
                               int* __restrict__ counter, int n) {
    int i = blockIdx.x * 256 + threadIdx.x;
    int lane = threadIdx.x & 63;
    int d = (i < n) ? deg[i] : 0;
    int scan = d;
    #pragma unroll
    for (int o = 1; o < 64; o <<= 1) {
        int v = __shfl_up(scan, o);
        if (lane >= o) scan += v;
    }
    int total = __shfl(scan, 63);
    int base = 0;
    if (lane == 63) base = atomicAdd(counter, total);
    base = __shfl(base, 63);
    if (i < n) offs[i] = base + scan - d;
}

// ---------------- fill CSR ----------------
__global__ void fill_kernel(const int* __restrict__ src, const int* __restrict__ dst,
                            const int* __restrict__ offs, int* __restrict__ cursor,
                            const float* __restrict__ dinv,
                            int* __restrict__ csr_src, float* __restrict__ csr_norm, int e) {
    int i = blockIdx.x * 256 + threadIdx.x;
    if (i >= e) return;
    int s = src[i], d = dst[i];
    int p = atomicAdd(&cursor[d], 1);
    int j = offs[d] + p;
    csr_src[j] = s;
    csr_norm[j] = dinv[s] * dinv[d];
}

// ---------------- graph boundaries from sorted batch ----------------
__global__ void bounds_kernel(const int* __restrict__ batch, int* __restrict__ gstart,
                              int n, int g) {
    int i = blockIdx.x * 256 + threadIdx.x;
    if (i >= n) return;
    int b = batch[i];
    int bp = (i == 0) ? -1 : batch[i - 1];
    for (int q = bp + 1; q <= b; ++q) gstart[q] = i;
    if (i == n - 1) {
        for (int q = b + 1; q <= g; ++q) gstart[q] = n;
    }
}

// ---------------- layer-0 GEMM: [N,7] @ [7,128] ----------------
__global__ void gemm7(const float* __restrict__ x, const float* __restrict__ W,
                      float* __restrict__ out, int n) {
    __shared__ float sW[7 * 128];
    int t = threadIdx.x;
    for (int i = t; i < 7 * 128; i += 256) sW[i] = W[i];
    __syncthreads();
    int idx = blockIdx.x * 256 + t;
    int row = idx >> 7, f = idx & 127;
    if (row < n) {
        const float* xr = x + (size_t)row * 7;
        float acc = 0.f;
        #pragma unroll
        for (int k = 0; k < 7; ++k) acc += xr[k] * sW[k * 128 + f];
        out[idx] = acc;
    }
}

// ---------------- 128x128 GEMM, 64-row tiles, 4x8 register tile ----------------
__launch_bounds__(256)
__global__ void gemm128(const float* __restrict__ h, const float* __restrict__ W,
                        float* __restrict__ out, int n) {
    __shared__ float sh[64 * 132];
    int t = threadIdx.x;
    int row0 = blockIdx.x * 64;
    int rows = n - row0; if (rows > 64) rows = 64;

    for (int idx4 = t * 4; idx4 < 64 * 128; idx4 += 1024) {
        int r = idx4 >> 7, k = idx4 & 127;
        float4 v;
        if (r < rows) v = *(const float4*)(h + (size_t)(row0 + r) * 128 + k);
        else          v = make_float4(0.f, 0.f, 0.f, 0.f);
        *(float4*)(&sh[r * 132 + k]) = v;
    }
    __syncthreads();

    int f0 = (t & 15) * 8;
    int r0 = (t >> 4) * 4;
    float acc[4][8];
    #pragma unroll
    for (int i = 0; i < 4; ++i)
        #pragma unroll
        for (int c = 0; c < 8; ++c) acc[i][c] = 0.f;

    for (int k0 = 0; k0 < 128; k0 += 4) {
        float a_s[4][4];
        #pragma unroll
        for (int i = 0; i < 4; ++i) {
            float4 v = *(const float4*)(&sh[(r0 + i) * 132 + k0]);
            a_s[i][0] = v.x; a_s[i][1] = v.y; a_s[i][2] = v.z; a_s[i][3] = v.w;
        }
        float w_s[4][8];
        #pragma unroll
        for (int j = 0; j < 4; ++j) {
            float4 w0 = *(const float4*)(W + (size_t)(k0 + j) * 128 + f0);
            float4 w1 = *(const float4*)(W + (size_t)(k0 + j) * 128 + f0 + 4);
            w_s[j][0] = w0.x; w_s[j][1] = w0.y; w_s[j][2] = w0.z; w_s[j][3] = w0.w;
            w_s[j][4] = w1.x; w_s[j][5] = w1.y; w_s[j][6] = w1.z; w_s[j][7] = w1.w;
        }
        #pragma unroll
        for (int j = 0; j < 4; ++j)
            #pragma unroll
            for (int i = 0; i < 4; ++i)
                #pragma unroll
                for (int c = 0; c < 8; ++c)
                    acc[i][c] = fmaf(a_s[i][j], w_s[j][c], acc[i][c]);
    }

    #pragma unroll
    for (int i = 0; i < 4; ++i) {
        if (r0 + i < rows) {
            float* op = out + (size_t)(row0 + r0 + i) * 128 + f0;
            *(float4*)op = make_float4(acc[i][0], acc[i][1], acc[i][2], acc[i][3]);
            *(float4*)(op + 4) = make_float4(acc[i][4], acc[i][5], acc[i][6], acc[i][7]);
        }
    }
}

// ---------------- aggregation + bias + BN + ReLU ----------------
// Wave per node; lane l owns features 2l, 2l+1 (float2). Edges processed in
// unrolled batches of 8 -> 8 outstanding dwordx2 loads before the waitcnt.
__launch_bounds__(256)
__global__ void agg_bn_relu(const float* __restrict__ hW, const int* __restrict__ csr_src,
                            const float* __restrict__ csr_norm, const int* __restrict__ offs,
                            const int* __restrict__ degi, const float* __restrict__ dinv,
                            const float* __restrict__ bias, const float* __restrict__ gamma,
                            const float* __restrict__ beta, const float* __restrict__ mean,
                            const float* __restrict__ var, float* __restrict__ out, int n) {
    int lane = threadIdx.x & 63;
    int node = blockIdx.x * 4 + (threadIdx.x >> 6);
    if (node >= n) return;
    float di = dinv[node];
    size_t base = (size_t)node * 128;
    int f0 = 2 * lane;
    float2 hv = *(const float2*)(hW + base + f0);
    float acc0 = di * di * hv.x;
    float acc1 = di * di * hv.y;
    int off = offs[node], cnt = degi[node];

    for (int b0 = 0; b0 < cnt; b0 += 64) {
        int j = b0 + lane;
        int s = 0; float nm = 0.f;
        if (j < cnt) { s = csr_src[off + j]; nm = csr_norm[off + j]; }
        int m = cnt - b0; if (m > 64) m = 64;
        int m8 = (m + 7) & ~7;   // padded lanes have nm=0, s=0 (row 0 is cache-hot)
        for (int e = 0; e < m8; e += 8) {
            float2 v[8]; float nn[8];
            #pragma unroll
            for (int u = 0; u < 8; ++u) {
                int ss = __shfl(s, e + u);
                nn[u] = __shfl(nm, e + u);
                v[u] = *(const float2*)(hW + (size_t)ss * 128 + f0);
            }
            #pragma unroll
            for (int u = 0; u < 8; ++u) {
                acc0 = fmaf(nn[u], v[u].x, acc0);
                acc1 = fmaf(nn[u], v[u].y, acc1);
            }
        }
    }

    float s0 = gamma[f0]     * rsqrtf(var[f0]     + EPSBN);
    float s1 = gamma[f0 + 1] * rsqrtf(var[f0 + 1] + EPSBN);
    float o0 = fmaf(s0, acc0 + bias[f0]     - mean[f0],     beta[f0]);
    float o1 = fmaf(s1, acc1 + bias[f0 + 1] - mean[f0 + 1], beta[f0 + 1]);
    float2 ov = make_float2(fmaxf(o0, 0.f), fmaxf(o1, 0.f));
    *(float2*)(out + base + f0) = ov;
}

// ---------------- segmented mean pool (no atomics; batch sorted) ----------------
__launch_bounds__(128)
__global__ void ligand_kernel(const float* __restrict__ h, const int* __restrict__ gstart,
                              float* __restrict__ lig) {
    int g = blockIdx.x, t = threadIdx.x;   // 128 threads = feature id
    int s = gstart[g], e = gstart[g + 1];
    float a0 = 0.f, a1 = 0.f, a2 = 0.f, a3 = 0.f;
    int i = s;
    for (; i + 4 <= e; i += 4) {
        a0 += h[(size_t)(i + 0) * 128 + t];
        a1 += h[(size_t)(i + 1) * 128 + t];
        a2 += h[(size_t)(i + 2) * 128 + t];
        a3 += h[(size_t)(i + 3) * 128 + t];
    }
    for (; i < e; ++i) a0 += h[(size_t)i * 128 + t];
    float c = (float)(e - s); if (c < 1.f) c = 1.f;
    lig[(size_t)g * 128 + t] = ((a0 + a1) + (a2 + a3)) / c;
}

// ---------------- pocket MLP: 28->64 relu ->64 ----------------
__global__ void pk_kernel(const float* __restrict__ pf, const float* __restrict__ W1,
                          const float* __restrict__ b1, const float* __restrict__ W2,
                          const float* __restrict__ b2, float* __restrict__ pk) {
    __shared__ float h1[64];
    int t = threadIdx.x;
    float acc = b1[t];
    #pragma unroll
    for (int k = 0; k < 28; ++k) acc = fmaf(pf[k], W1[k * 64 + t], acc);
    h1[t] = fmaxf(acc, 0.f);
    __syncthreads();
    float acc2 = b2[t];
    for (int k = 0; k < 64; ++k) acc2 = fmaf(h1[k], W2[k * 64 + t], acc2);
    pk[t] = acc2;
}

// ---------------- fold bilinear: M[o,i] = sum_j bilW[o,i,j] * pk[j] ----------------
__global__ void bilM_kernel(const float* __restrict__ bilW, const float* __restrict__ pk,
                            float* __restrict__ M) {
    __shared__ float spk[64];
    int t = threadIdx.x;
    if (t < 64) spk[t] = pk[t];
    __syncthreads();
    int idx = blockIdx.x * 256 + t;
    if (idx < 64 * 128) {
        const float* wr = bilW + (size_t)idx * 64;
        float acc = 0.f;
        #pragma unroll 8
        for (int j = 0; j < 64; ++j) acc = fmaf(wr[j], spk[j], acc);
        M[idx] = acc;
    }
}

// ---------------- per-graph tail ----------------
__global__ void final_kernel(const float* __restrict__ lig_in, const float* __restrict__ M,
                             const float* __restrict__ bil_b,
                             const float* __restrict__ cW1, const float* __restrict__ cb1,
                             const float* __restrict__ cW2, const float* __restrict__ cb2,
                             float* __restrict__ out) {
    __shared__ float lig[128];
    __shared__ float inter[64];
    __shared__ float hc[32];
    int g = blockIdx.x, t = threadIdx.x;
    lig[t] = lig_in[(size_t)g * 128 + t];
    __syncthreads();
    if (t < 64) {
        float acc = bil_b[t];
        const float* mr = M + (size_t)t * 128;
        #pragma unroll 8
        for (int i = 0; i < 128; ++i) acc = fmaf(lig[i], mr[i], acc);
        inter[t] = acc;
    }
    __syncthreads();
    if (t < 32) {
        float acc = cb1[t];
        #pragma unroll 8
        for (int o = 0; o < 64; ++o) acc = fmaf(inter[o], cW1[o * 32 + t], acc);
        hc[t] = fmaxf(acc, 0.f);
    }
    __syncthreads();
    if (t == 0) {
        float acc = cb2[0];
        #pragma unroll
        for (int j = 0; j < 32; ++j) acc = fmaf(hc[j], cW2[j], acc);
        out[g] = acc;
    }
}

extern "C" void kernel_launch(void* const* d_in, const int* in_sizes, int n_in,
                              void* d_out, int out_size, void* d_ws, size_t ws_size,
                              hipStream_t stream) {
    const float* x        = (const float*)d_in[0];
    const int*   edge     = (const int*)d_in[1];
    const int*   batch    = (const int*)d_in[2];
    const float* pocket   = (const float*)d_in[3];
    const float* conv0_W  = (const float*)d_in[4];
    const float* conv0_b  = (const float*)d_in[5];
    const float* convs_W  = (const float*)d_in[6];
    const float* convs_b  = (const float*)d_in[7];
    const float* bn_gamma = (const float*)d_in[8];
    const float* bn_beta  = (const float*)d_in[9];
    const float* bn_mean  = (const float*)d_in[10];
    const float* bn_var   = (const float*)d_in[11];
    const float* pmlp_W1  = (const float*)d_in[12];
    const float* pmlp_b1  = (const float*)d_in[13];
    const float* pmlp_W2  = (const float*)d_in[14];
    const float* pmlp_b2  = (const float*)d_in[15];
    const float* bil_W    = (const float*)d_in[16];
    const float* bil_b    = (const float*)d_in[17];
    const float* cls_W1   = (const float*)d_in[18];
    const float* cls_b1   = (const float*)d_in[19];
    const float* cls_W2   = (const float*)d_in[20];
    const float* cls_b2   = (const float*)d_in[21];

    const int N = in_sizes[0] / 7;
    const int E = in_sizes[1] / 2;
    const int G = out_size;
    const int* srcA = edge;
    const int* dstA = edge + E;

    char* p = (char*)d_ws;
    auto alloc = [&](size_t bytes) -> void* {
        void* r = (void*)p;
        p += (bytes + 255) & ~(size_t)255;
        return r;
    };
    int*   deg      = (int*)alloc((size_t)N * 4);
    int*   cursor   = (int*)alloc((size_t)N * 4);
    int*   offs     = (int*)alloc((size_t)N * 4);
    int*   counter  = (int*)alloc(256);
    float* dinv     = (float*)alloc((size_t)N * 4);
    int*   csr_src  = (int*)alloc((size_t)E * 4);
    float* csr_norm = (float*)alloc((size_t)E * 4);
    float* bufA     = (float*)alloc((size_t)N * 128 * 4);
    float* bufB     = (float*)alloc((size_t)N * 128 * 4);
    int*   gstart   = (int*)alloc((size_t)(G + 1) * 4);
    float* lig      = (float*)alloc((size_t)G * 128 * 4);
    float* pk       = (float*)alloc(64 * 4);
    float* M        = (float*)alloc(64 * 128 * 4);

    init_kernel<<<(N + 255) / 256, 256, 0, stream>>>(deg, cursor, counter, N);
    count_kernel<<<(E + 255) / 256, 256, 0, stream>>>(dstA, deg, E);
    dinv_kernel<<<(N + 255) / 256, 256, 0, stream>>>(deg, dinv, N);
    reserve_kernel<<<(N + 255) / 256, 256, 0, stream>>>(deg, offs, counter, N);
    fill_kernel<<<(E + 255) / 256, 256, 0, stream>>>(srcA, dstA, offs, cursor, dinv,
                                                     csr_src, csr_norm, E);
    bounds_kernel<<<(N + 255) / 256, 256, 0, stream>>>(batch, gstart, N, G);

    // layer 0
    gemm7<<<((size_t)N * 128 + 255) / 256, 256, 0, stream>>>(x, conv0_W, bufA, N);
    agg_bn_relu<<<(N + 3) / 4, 256, 0, stream>>>(bufA, csr_src, csr_norm, offs, deg, dinv,
                                                 conv0_b, bn_gamma, bn_beta, bn_mean, bn_var,
                                                 bufB, N);
    // layer 1
    gemm128<<<(N + 63) / 64, 256, 0, stream>>>(bufB, convs_W, bufA, N);
    agg_bn_relu<<<(N + 3) / 4, 256, 0, stream>>>(bufA, csr_src, csr_norm, offs, deg, dinv,
                                                 convs_b, bn_gamma + 128, bn_beta + 128,
                                                 bn_mean + 128, bn_var + 128, bufB, N);
    // layer 2
    gemm128<<<(N + 63) / 64, 256, 0, stream>>>(bufB, convs_W + 128 * 128, bufA, N);
    agg_bn_relu<<<(N + 3) / 4, 256, 0, stream>>>(bufA, csr_src, csr_norm, offs, deg, dinv,
                                                 convs_b + 128, bn_gamma + 256, bn_beta + 256,
                                                 bn_mean + 256, bn_var + 256, bufB, N);

    ligand_kernel<<<G, 128, 0, stream>>>(bufB, gstart, lig);
    pk_kernel<<<1, 64, 0, stream>>>(pocket, pmlp_W1, pmlp_b1, pmlp_W2, pmlp_b2, pk);
    bilM_kernel<<<32, 256, 0, stream>>>(bil_W, pk, M);
    final_kernel<<<G, 128, 0, stream>>>(lig, M, bil_b, cls_W1, cls_b1, cls_W2, cls_b2,
                                        (float*)d_out);
}

// Round 3
// 564.223 us; speedup vs baseline: 1.6460x; 1.2788x over previous
//
#include <hip/hip_runtime.h>
#include <hip/hip_bf16.h>

#define EPSBN 1e-5f

__device__ inline float bf_lo(unsigned int w) { return __uint_as_float(w << 16); }
__device__ inline float bf_hi(unsigned int w) { return __uint_as_float(w & 0xffff0000u); }
__device__ inline unsigned short f2bf(float v) {
    __hip_bfloat16 b = __float2bfloat16(v);
    return *(unsigned short*)&b;
}

// ---------------- init ----------------
__global__ void init_kernel(int* __restrict__ deg, int* __restrict__ counter, int n) {
    int i = blockIdx.x * 256 + threadIdx.x;
    if (i < n) deg[i] = 0;
    if (i == 0) *counter = 0;
}

// ---------------- degree count ----------------
__global__ void count_kernel(const int* __restrict__ dst, int* __restrict__ deg, int e) {
    int i = blockIdx.x * 256 + threadIdx.x;
    if (i < e) atomicAdd(&deg[dst[i]], 1);
}

// ---------------- reserve CSR ranges + dinv (wave-aggregated atomic) ----------------
__global__ void reserve_kernel(const int* __restrict__ deg, int* __restrict__ offs,
                               int* __restrict__ cursor, float* __restrict__ dinv,
                               int* __restrict__ counter, int n) {
    int i = blockIdx.x * 256 + threadIdx.x;
    int lane = threadIdx.x & 63;
    int d = (i < n) ? deg[i] : 0;
    int scan = d;
    #pragma unroll
    for (int o = 1; o < 64; o <<= 1) {
        int v = __shfl_up(scan, o);
        if (lane >= o) scan += v;
    }
    int total = __shfl(scan, 63);
    int base = 0;
    if (lane == 63) base = atomicAdd(counter, total);
    base = __shfl(base, 63);
    if (i < n) {
        int o = base + scan - d;
        offs[i] = o;
        cursor[i] = o;                    // fill's atomic returns global slot
        dinv[i] = rsqrtf((float)d + 1.0f);
    }
}

// ---------------- fill CSR (src only, 4B/edge scatter) ----------------
__global__ void fill_kernel(const int* __restrict__ src, const int* __restrict__ dst,
                            int* __restrict__ cursor, int* __restrict__ csr_src, int e) {
    int i = blockIdx.x * 256 + threadIdx.x;
    if (i >= e) return;
    int s = src[i], d = dst[i];
    int p = atomicAdd(&cursor[d], 1);
    csr_src[p] = s;
}

// ---------------- graph boundaries from sorted batch ----------------
__global__ void bounds_kernel(const int* __restrict__ batch, int* __restrict__ gstart,
                              int n, int g) {
    int i = blockIdx.x * 256 + threadIdx.x;
    if (i >= n) return;
    int b = batch[i];
    int bp = (i == 0) ? -1 : batch[i - 1];
    for (int q = bp + 1; q <= b; ++q) gstart[q] = i;
    if (i == n - 1) {
        for (int q = b + 1; q <= g; ++q) gstart[q] = n;
    }
}

// ---------------- fold BN: sc = g*rsqrt(v+eps); sh = sc*(bias-mean)+beta ----------------
__global__ void bnfold_kernel(const float* __restrict__ conv0_b, const float* __restrict__ convs_b,
                              const float* __restrict__ gamma, const float* __restrict__ beta,
                              const float* __restrict__ mean, const float* __restrict__ var,
                              float* __restrict__ sc, float* __restrict__ sh) {
    int i = threadIdx.x;            // 384 = 3 layers x 128
    if (i >= 384) return;
    int l = i >> 7, f = i & 127;
    float bias = (l == 0) ? conv0_b[f] : convs_b[(l - 1) * 128 + f];
    float s = gamma[i] * rsqrtf(var[i] + EPSBN);
    sc[i] = s;
    sh[i] = fmaf(s, bias - mean[i], beta[i]);
}

// ---------------- layer-0: aggregate raw 7-dim features (28B/edge gather) ----------------
// Wave per node; lane = e*8+f : 8 edge-slots x 8 feature-slots (f<7 active).
__launch_bounds__(256)
__global__ void agg7(const float* __restrict__ x, const int* __restrict__ csr_src,
                     const int* __restrict__ offs, const int* __restrict__ degi,
                     const float* __restrict__ dinv, float* __restrict__ xa, int n) {
    int lane = threadIdx.x & 63;
    int node = blockIdx.x * 4 + (threadIdx.x >> 6);
    if (node >= n) return;
    int e = lane >> 3, f = lane & 7;
    int off = offs[node], cnt = degi[node];
    float di = dinv[node];
    float acc = 0.f, accB = 0.f;
    for (int b0 = 0; b0 < cnt; b0 += 64) {
        int j = b0 + lane;
        int s = 0; float dv = 0.f;
        if (j < cnt) { s = csr_src[off + j]; dv = dinv[s]; }
        int m = cnt - b0; if (m > 64) m = 64;
        int m16 = (m + 15) & ~15;
        for (int i2 = 0; i2 < m16; i2 += 16) {
            int ss1 = __shfl(s, i2 + e);
            int ss2 = __shfl(s, i2 + 8 + e);
            float d1 = __shfl(dv, i2 + e);
            float d2 = __shfl(dv, i2 + 8 + e);
            float v1 = 0.f, v2 = 0.f;
            if (f < 7) {
                v1 = d1 * x[(size_t)ss1 * 7 + f];   // d=0 on pad lanes
                v2 = d2 * x[(size_t)ss2 * 7 + f];
            }
            acc += v1; accB += v2;
        }
    }
    acc += accB;
    acc += __shfl_xor(acc, 8);
    acc += __shfl_xor(acc, 16);
    acc += __shfl_xor(acc, 32);
    if (e == 0 && f < 7) {
        float self = di * x[(size_t)node * 7 + f];
        xa[(size_t)node * 7 + f] = di * (acc + self);
    }
}

// ---------------- layer-0 dense: xa[N,7] @ W0[7,128] + foldedBN + relu ----------------
__global__ void l0_dense(const float* __restrict__ xa, const float* __restrict__ W,
                         const float* __restrict__ sc, const float* __restrict__ sh,
                         float* __restrict__ out, int n) {
    __shared__ float sW[7 * 128];
    int t = threadIdx.x;
    for (int i = t; i < 7 * 128; i += 256) sW[i] = W[i];
    __syncthreads();
    int idx = blockIdx.x * 256 + t;
    int row = idx >> 7, f = idx & 127;
    if (row < n) {
        const float* xr = xa + (size_t)row * 7;
        float a = 0.f;
        #pragma unroll
        for (int k = 0; k < 7; ++k) a = fmaf(xr[k], sW[k * 128 + f], a);
        out[idx] = fmaxf(fmaf(sc[f], a, sh[f]), 0.f);
    }
}

// ---------------- 128x128 GEMM fp32 -> bf16 output ----------------
__launch_bounds__(256)
__global__ void gemm128_bf16(const float* __restrict__ h, const float* __restrict__ W,
                             unsigned short* __restrict__ out, int n) {
    __shared__ float sh[64 * 132];
    int t = threadIdx.x;
    int row0 = blockIdx.x * 64;
    int rows = n - row0; if (rows > 64) rows = 64;

    for (int idx4 = t * 4; idx4 < 64 * 128; idx4 += 1024) {
        int r = idx4 >> 7, k = idx4 & 127;
        float4 v;
        if (r < rows) v = *(const float4*)(h + (size_t)(row0 + r) * 128 + k);
        else          v = make_float4(0.f, 0.f, 0.f, 0.f);
        *(float4*)(&sh[r * 132 + k]) = v;
    }
    __syncthreads();

    int f0 = (t & 15) * 8;
    int r0 = (t >> 4) * 4;
    float acc[4][8];
    #pragma unroll
    for (int i = 0; i < 4; ++i)
        #pragma unroll
        for (int c = 0; c < 8; ++c) acc[i][c] = 0.f;

    for (int k0 = 0; k0 < 128; k0 += 4) {
        float a_s[4][4];
        #pragma unroll
        for (int i = 0; i < 4; ++i) {
            float4 v = *(const float4*)(&sh[(r0 + i) * 132 + k0]);
            a_s[i][0] = v.x; a_s[i][1] = v.y; a_s[i][2] = v.z; a_s[i][3] = v.w;
        }
        float w_s[4][8];
        #pragma unroll
        for (int j = 0; j < 4; ++j) {
            float4 w0 = *(const float4*)(W + (size_t)(k0 + j) * 128 + f0);
            float4 w1 = *(const float4*)(W + (size_t)(k0 + j) * 128 + f0 + 4);
            w_s[j][0] = w0.x; w_s[j][1] = w0.y; w_s[j][2] = w0.z; w_s[j][3] = w0.w;
            w_s[j][4] = w1.x; w_s[j][5] = w1.y; w_s[j][6] = w1.z; w_s[j][7] = w1.w;
        }
        #pragma unroll
        for (int j = 0; j < 4; ++j)
            #pragma unroll
            for (int i = 0; i < 4; ++i)
                #pragma unroll
                for (int c = 0; c < 8; ++c)
                    acc[i][c] = fmaf(a_s[i][j], w_s[j][c], acc[i][c]);
    }

    #pragma unroll
    for (int i = 0; i < 4; ++i) {
        if (r0 + i < rows) {
            uint4 o;
            o.x = (unsigned int)f2bf(acc[i][0]) | ((unsigned int)f2bf(acc[i][1]) << 16);
            o.y = (unsigned int)f2bf(acc[i][2]) | ((unsigned int)f2bf(acc[i][3]) << 16);
            o.z = (unsigned int)f2bf(acc[i][4]) | ((unsigned int)f2bf(acc[i][5]) << 16);
            o.w = (unsigned int)f2bf(acc[i][6]) | ((unsigned int)f2bf(acc[i][7]) << 16);
            *(uint4*)(out + (size_t)(row0 + r0 + i) * 128 + f0) = o;
        }
    }
}

// ---------------- aggregation over bf16 table + foldedBN + ReLU ----------------
// Wave per node; lane owns features 2l,2l+1 (one u32 = 2 bf16). ILP-8 edge batches.
__launch_bounds__(256)
__global__ void agg_bf16(const unsigned int* __restrict__ hw32, const int* __restrict__ csr_src,
                         const int* __restrict__ offs, const int* __restrict__ degi,
                         const float* __restrict__ dinv,
                         const float* __restrict__ sc, const float* __restrict__ shv,
                         float* __restrict__ out, int n) {
    int lane = threadIdx.x & 63;
    int node = blockIdx.x * 4 + (threadIdx.x >> 6);
    if (node >= n) return;
    float di = dinv[node];
    int f0 = 2 * lane;
    unsigned int wself = hw32[(size_t)node * 64 + lane];
    float acc0 = di * bf_lo(wself);
    float acc1 = di * bf_hi(wself);
    int off = offs[node], cnt = degi[node];

    for (int b0 = 0; b0 < cnt; b0 += 64) {
        int j = b0 + lane;
        int s = 0; float dv = 0.f;
        if (j < cnt) { s = csr_src[off + j]; dv = dinv[s]; }
        int m = cnt - b0; if (m > 64) m = 64;
        int m8 = (m + 7) & ~7;
        for (int e = 0; e < m8; e += 8) {
            unsigned int w[8]; float nn[8];
            #pragma unroll
            for (int u = 0; u < 8; ++u) {
                int ss = __shfl(s, e + u);
                nn[u] = __shfl(dv, e + u);           // 0 on pad lanes
                w[u] = hw32[(size_t)ss * 64 + lane];
            }
            #pragma unroll
            for (int u = 0; u < 8; ++u) {
                acc0 = fmaf(nn[u], bf_lo(w[u]), acc0);
                acc1 = fmaf(nn[u], bf_hi(w[u]), acc1);
            }
        }
    }
    acc0 *= di;  // norm = dinv[s]*dinv[d]; self = di^2
    acc1 *= di;
    float o0 = fmaf(sc[f0],     acc0, shv[f0]);
    float o1 = fmaf(sc[f0 + 1], acc1, shv[f0 + 1]);
    *(float2*)(out + (size_t)node * 128 + f0) = make_float2(fmaxf(o0, 0.f), fmaxf(o1, 0.f));
}

// ---------------- segmented mean pool ----------------
__launch_bounds__(128)
__global__ void ligand_kernel(const float* __restrict__ h, const int* __restrict__ gstart,
                              float* __restrict__ lig) {
    int g = blockIdx.x, t = threadIdx.x;
    int s = gstart[g], e = gstart[g + 1];
    float a0 = 0.f, a1 = 0.f, a2 = 0.f, a3 = 0.f;
    int i = s;
    for (; i + 4 <= e; i += 4) {
        a0 += h[(size_t)(i + 0) * 128 + t];
        a1 += h[(size_t)(i + 1) * 128 + t];
        a2 += h[(size_t)(i + 2) * 128 + t];
        a3 += h[(size_t)(i + 3) * 128 + t];
    }
    for (; i < e; ++i) a0 += h[(size_t)i * 128 + t];
    float c = (float)(e - s); if (c < 1.f) c = 1.f;
    lig[(size_t)g * 128 + t] = ((a0 + a1) + (a2 + a3)) / c;
}

// ---------------- pocket MLP ----------------
__global__ void pk_kernel(const float* __restrict__ pf, const float* __restrict__ W1,
                          const float* __restrict__ b1, const float* __restrict__ W2,
                          const float* __restrict__ b2, float* __restrict__ pk) {
    __shared__ float h1[64];
    int t = threadIdx.x;
    float acc = b1[t];
    #pragma unroll
    for (int k = 0; k < 28; ++k) acc = fmaf(pf[k], W1[k * 64 + t], acc);
    h1[t] = fmaxf(acc, 0.f);
    __syncthreads();
    float acc2 = b2[t];
    for (int k = 0; k < 64; ++k) acc2 = fmaf(h1[k], W2[k * 64 + t], acc2);
    pk[t] = acc2;
}

// ---------------- fold bilinear ----------------
__global__ void bilM_kernel(const float* __restrict__ bilW, const float* __restrict__ pk,
                            float* __restrict__ M) {
    __shared__ float spk[64];
    int t = threadIdx.x;
    if (t < 64) spk[t] = pk[t];
    __syncthreads();
    int idx = blockIdx.x * 256 + t;
    if (idx < 64 * 128) {
        const float* wr = bilW + (size_t)idx * 64;
        float acc = 0.f;
        #pragma unroll 8
        for (int j = 0; j < 64; ++j) acc = fmaf(wr[j], spk[j], acc);
        M[idx] = acc;
    }
}

// ---------------- per-graph tail ----------------
__global__ void final_kernel(const float* __restrict__ lig_in, const float* __restrict__ M,
                             const float* __restrict__ bil_b,
                             const float* __restrict__ cW1, const float* __restrict__ cb1,
                             const float* __restrict__ cW2, const float* __restrict__ cb2,
                             float* __restrict__ out) {
    __shared__ float lig[128];
    __shared__ float inter[64];
    __shared__ float hc[32];
    int g = blockIdx.x, t = threadIdx.x;
    lig[t] = lig_in[(size_t)g * 128 + t];
    __syncthreads();
    if (t < 64) {
        float acc = bil_b[t];
        const float* mr = M + (size_t)t * 128;
        #pragma unroll 8
        for (int i = 0; i < 128; ++i) acc = fmaf(lig[i], mr[i], acc);
        inter[t] = acc;
    }
    __syncthreads();
    if (t < 32) {
        float acc = cb1[t];
        #pragma unroll 8
        for (int o = 0; o < 64; ++o) acc = fmaf(inter[o], cW1[o * 32 + t], acc);
        hc[t] = fmaxf(acc, 0.f);
    }
    __syncthreads();
    if (t == 0) {
        float acc = cb2[0];
        #pragma unroll
        for (int j = 0; j < 32; ++j) acc = fmaf(hc[j], cW2[j], acc);
        out[g] = acc;
    }
}

extern "C" void kernel_launch(void* const* d_in, const int* in_sizes, int n_in,
                              void* d_out, int out_size, void* d_ws, size_t ws_size,
                              hipStream_t stream) {
    const float* x        = (const float*)d_in[0];
    const int*   edge     = (const int*)d_in[1];
    const int*   batch    = (const int*)d_in[2];
    const float* pocket   = (const float*)d_in[3];
    const float* conv0_W  = (const float*)d_in[4];
    const float* conv0_b  = (const float*)d_in[5];
    const float* convs_W  = (const float*)d_in[6];
    const float* convs_b  = (const float*)d_in[7];
    const float* bn_gamma = (const float*)d_in[8];
    const float* bn_beta  = (const float*)d_in[9];
    const float* bn_mean  = (const float*)d_in[10];
    const float* bn_var   = (const float*)d_in[11];
    const float* pmlp_W1  = (const float*)d_in[12];
    const float* pmlp_b1  = (const float*)d_in[13];
    const float* pmlp_W2  = (const float*)d_in[14];
    const float* pmlp_b2  = (const float*)d_in[15];
    const float* bil_W    = (const float*)d_in[16];
    const float* bil_b    = (const float*)d_in[17];
    const float* cls_W1   = (const float*)d_in[18];
    const float* cls_b1   = (const float*)d_in[19];
    const float* cls_W2   = (const float*)d_in[20];
    const float* cls_b2   = (const float*)d_in[21];

    const int N = in_sizes[0] / 7;
    const int E = in_sizes[1] / 2;
    const int G = out_size;
    const int* srcA = edge;
    const int* dstA = edge + E;

    char* p = (char*)d_ws;
    auto alloc = [&](size_t bytes) -> void* {
        void* r = (void*)p;
        p += (bytes + 255) & ~(size_t)255;
        return r;
    };
    int*   deg      = (int*)alloc((size_t)N * 4);
    int*   cursor   = (int*)alloc((size_t)N * 4);
    int*   offs     = (int*)alloc((size_t)N * 4);
    int*   counter  = (int*)alloc(256);
    float* dinv     = (float*)alloc((size_t)N * 4);
    int*   csr_src  = (int*)alloc((size_t)E * 4);
    float* xa       = (float*)alloc((size_t)N * 7 * 4);
    unsigned short* bufH = (unsigned short*)alloc((size_t)N * 128 * 2);  // bf16 gather table
    float* bufF     = (float*)alloc((size_t)N * 128 * 4);                // fp32 layer output
    int*   gstart   = (int*)alloc((size_t)(G + 1) * 4);
    float* lig      = (float*)alloc((size_t)G * 128 * 4);
    float* pk       = (float*)alloc(64 * 4);
    float* M        = (float*)alloc(64 * 128 * 4);
    float* sc       = (float*)alloc(384 * 4);
    float* shv      = (float*)alloc(384 * 4);

    init_kernel<<<(N + 255) / 256, 256, 0, stream>>>(deg, counter, N);
    count_kernel<<<(E + 255) / 256, 256, 0, stream>>>(dstA, deg, E);
    reserve_kernel<<<(N + 255) / 256, 256, 0, stream>>>(deg, offs, cursor, dinv, counter, N);
    fill_kernel<<<(E + 255) / 256, 256, 0, stream>>>(srcA, dstA, cursor, csr_src, E);
    bounds_kernel<<<(N + 255) / 256, 256, 0, stream>>>(batch, gstart, N, G);
    bnfold_kernel<<<1, 384, 0, stream>>>(conv0_b, convs_b, bn_gamma, bn_beta, bn_mean, bn_var,
                                         sc, shv);

    // layer 0: agg(x) then dense 7->128 (+BN+relu)
    agg7<<<(N + 3) / 4, 256, 0, stream>>>(x, csr_src, offs, deg, dinv, xa, N);
    l0_dense<<<((size_t)N * 128 + 255) / 256, 256, 0, stream>>>(xa, conv0_W, sc, shv, bufF, N);

    // layer 1
    gemm128_bf16<<<(N + 63) / 64, 256, 0, stream>>>(bufF, convs_W, bufH, N);
    agg_bf16<<<(N + 3) / 4, 256, 0, stream>>>((const unsigned int*)bufH, csr_src, offs, deg,
                                              dinv, sc + 128, shv + 128, bufF, N);
    // layer 2
    gemm128_bf16<<<(N + 63) / 64, 256, 0, stream>>>(bufF, convs_W + 128 * 128, bufH, N);
    agg_bf16<<<(N + 3) / 4, 256, 0, stream>>>((const unsigned int*)bufH, csr_src, offs, deg,
                                              dinv, sc + 256, shv + 256, bufF, N);

    ligand_kernel<<<G, 128, 0, stream>>>(bufF, gstart, lig);
    pk_kernel<<<1, 64, 0, stream>>>(pocket, pmlp_W1, pmlp_b1, pmlp_W2, pmlp_b2, pk);
    bilM_kernel<<<32, 256, 0, stream>>>(bil_W, pk, M);
    final_kernel<<<G, 128, 0, stream>>>(lig, M, bil_b, cls_W1, cls_b1, cls_W2, cls_b2,
                                        (float*)d_out);
}

// Round 4
// 512.771 us; speedup vs baseline: 1.8111x; 1.1003x over previous
//
#include <hip/hip_runtime.h>
#include <hip/hip_bf16.h>

#define EPSBN 1e-5f

__device__ inline float bf_lo(unsigned int w) { return __uint_as_float(w << 16); }
__device__ inline float bf_hi(unsigned int w) { return __uint_as_float(w & 0xffff0000u); }
__device__ inline unsigned short f2bf(float v) {
    __hip_bfloat16 b = __float2bfloat16(v);
    return *(unsigned short*)&b;
}

// ---------------- init ----------------
__global__ void init_kernel(int* __restrict__ deg, int n) {
    int i = blockIdx.x * 256 + threadIdx.x;
    if (i < n) deg[i] = 0;
}

// ---------------- degree count (XCD-colored dst windows) ----------------
__global__ void count_kernel(const int* __restrict__ dst, int* __restrict__ deg,
                             int e, int n) {
    int c = blockIdx.x & 7;
    int lo = (int)((long long)n * c >> 3);
    int hi = (int)((long long)n * (c + 1) >> 3);
    int stride = (gridDim.x >> 3) * 256;
    for (int i = (blockIdx.x >> 3) * 256 + threadIdx.x; i < e; i += stride) {
        int d = dst[i];
        if (d >= lo && d < hi) atomicAdd(&deg[d], 1);
    }
}

// ---------------- deterministic scan: per-block sums ----------------
__global__ void blocksum_kernel(const int* __restrict__ deg, int* __restrict__ bsum, int n) {
    int i = blockIdx.x * 256 + threadIdx.x;
    int v = (i < n) ? deg[i] : 0;
    #pragma unroll
    for (int o = 1; o < 64; o <<= 1) v += __shfl_xor(v, o);
    __shared__ int ws[4];
    if ((threadIdx.x & 63) == 0) ws[threadIdx.x >> 6] = v;
    __syncthreads();
    if (threadIdx.x == 0) bsum[blockIdx.x] = ws[0] + ws[1] + ws[2] + ws[3];
}

// ---------------- scan of block sums (single block) ----------------
__global__ void scansum_kernel(int* __restrict__ bsum, int nb) {
    __shared__ int tot;
    __shared__ int wsum[4];
    if (threadIdx.x == 0) tot = 0;
    __syncthreads();
    for (int base = 0; base < nb; base += 256) {
        int i = base + threadIdx.x;
        int v = (i < nb) ? bsum[i] : 0;
        int lane = threadIdx.x & 63, w = threadIdx.x >> 6;
        int sc = v;
        #pragma unroll
        for (int o = 1; o < 64; o <<= 1) {
            int u = __shfl_up(sc, o);
            if (lane >= o) sc += u;
        }
        if (lane == 63) wsum[w] = sc;
        __syncthreads();
        int wbase = 0;
        for (int q = 0; q < w; ++q) wbase += wsum[q];
        int excl = tot + wbase + sc - v;
        if (i < nb) bsum[i] = excl;
        __syncthreads();
        if (threadIdx.x == 255) tot = excl + v;
        __syncthreads();
    }
}

// ---------------- offs = bsum[block] + in-block exclusive scan; cursor; dinv ----------------
__global__ void offs_kernel(const int* __restrict__ deg, const int* __restrict__ bsum,
                            int* __restrict__ offs, int* __restrict__ cursor,
                            float* __restrict__ dinv, int n) {
    int i = blockIdx.x * 256 + threadIdx.x;
    int v = (i < n) ? deg[i] : 0;
    int lane = threadIdx.x & 63, w = threadIdx.x >> 6;
    int sc = v;
    #pragma unroll
    for (int o = 1; o < 64; o <<= 1) {
        int u = __shfl_up(sc, o);
        if (lane >= o) sc += u;
    }
    __shared__ int wsum[4];
    if (lane == 63) wsum[w] = sc;
    __syncthreads();
    int wbase = 0;
    for (int q = 0; q < w; ++q) wbase += wsum[q];
    if (i < n) {
        int o = bsum[blockIdx.x] + wbase + sc - v;
        offs[i] = o;
        cursor[i] = o;
        dinv[i] = rsqrtf((float)v + 1.0f);
    }
}

// ---------------- fill CSR (u16 payload, XCD-colored dst windows) ----------------
__global__ void fill_kernel(const int* __restrict__ src, const int* __restrict__ dst,
                            int* __restrict__ cursor, unsigned short* __restrict__ csr,
                            int e, int n) {
    int c = blockIdx.x & 7;
    int lo = (int)((long long)n * c >> 3);
    int hi = (int)((long long)n * (c + 1) >> 3);
    int stride = (gridDim.x >> 3) * 256;
    for (int i = (blockIdx.x >> 3) * 256 + threadIdx.x; i < e; i += stride) {
        int d = dst[i];
        if (d >= lo && d < hi) {
            int p = atomicAdd(&cursor[d], 1);
            csr[p] = (unsigned short)src[i];
        }
    }
}

// ---------------- graph boundaries from sorted batch ----------------
__global__ void bounds_kernel(const int* __restrict__ batch, int* __restrict__ gstart,
                              int n, int g) {
    int i = blockIdx.x * 256 + threadIdx.x;
    if (i >= n) return;
    int b = batch[i];
    int bp = (i == 0) ? -1 : batch[i - 1];
    for (int q = bp + 1; q <= b; ++q) gstart[q] = i;
    if (i == n - 1) {
        for (int q = b + 1; q <= g; ++q) gstart[q] = n;
    }
}

// ---------------- fold BN ----------------
__global__ void bnfold_kernel(const float* __restrict__ conv0_b, const float* __restrict__ convs_b,
                              const float* __restrict__ gamma, const float* __restrict__ beta,
                              const float* __restrict__ mean, const float* __restrict__ var,
                              float* __restrict__ sc, float* __restrict__ sh) {
    int i = threadIdx.x;
    if (i >= 384) return;
    int l = i >> 7, f = i & 127;
    float bias = (l == 0) ? conv0_b[f] : convs_b[(l - 1) * 128 + f];
    float s = gamma[i] * rsqrtf(var[i] + EPSBN);
    sc[i] = s;
    sh[i] = fmaf(s, bias - mean[i], beta[i]);
}

// ---------------- layer-0: aggregate raw 7-dim features ----------------
__launch_bounds__(256)
__global__ void agg7(const float* __restrict__ x, const unsigned short* __restrict__ csr,
                     const int* __restrict__ offs, const int* __restrict__ degi,
                     const float* __restrict__ dinv, float* __restrict__ xa, int n) {
    int lane = threadIdx.x & 63;
    int node = blockIdx.x * 4 + (threadIdx.x >> 6);
    if (node >= n) return;
    int e = lane >> 3, f = lane & 7;
    int off = offs[node], cnt = degi[node];
    float di = dinv[node];
    float acc = 0.f, accB = 0.f;
    for (int b0 = 0; b0 < cnt; b0 += 64) {
        int j = b0 + lane;
        int s = 0; float dv = 0.f;
        if (j < cnt) { s = csr[off + j]; dv = dinv[s]; }
        int m = cnt - b0; if (m > 64) m = 64;
        int m16 = (m + 15) & ~15;
        for (int i2 = 0; i2 < m16; i2 += 16) {
            int ss1 = __shfl(s, i2 + e);
            int ss2 = __shfl(s, i2 + 8 + e);
            float d1 = __shfl(dv, i2 + e);
            float d2 = __shfl(dv, i2 + 8 + e);
            float v1 = 0.f, v2 = 0.f;
            if (f < 7) {
                v1 = d1 * x[(size_t)ss1 * 7 + f];
                v2 = d2 * x[(size_t)ss2 * 7 + f];
            }
            acc += v1; accB += v2;
        }
    }
    acc += accB;
    acc += __shfl_xor(acc, 8);
    acc += __shfl_xor(acc, 16);
    acc += __shfl_xor(acc, 32);
    if (e == 0 && f < 7) {
        float self = di * x[(size_t)node * 7 + f];
        xa[(size_t)node * 7 + f] = di * (acc + self);
    }
}

// ---------------- layer-0 dense: xa[N,7] @ W0[7,128] + foldedBN + relu ----------------
__global__ void l0_dense(const float* __restrict__ xa, const float* __restrict__ W,
                         const float* __restrict__ sc, const float* __restrict__ sh,
                         float* __restrict__ out, int n) {
    __shared__ float sW[7 * 128];
    int t = threadIdx.x;
    for (int i = t; i < 7 * 128; i += 256) sW[i] = W[i];
    __syncthreads();
    int idx = blockIdx.x * 256 + t;
    int row = idx >> 7, f = idx & 127;
    if (row < n) {
        const float* xr = xa + (size_t)row * 7;
        float a = 0.f;
        #pragma unroll
        for (int k = 0; k < 7; ++k) a = fmaf(xr[k], sW[k * 128 + f], a);
        out[idx] = fmaxf(fmaf(sc[f], a, sh[f]), 0.f);
    }
}

// ---------------- 128x128 GEMM fp32 -> bf16 output ----------------
__launch_bounds__(256)
__global__ void gemm128_bf16(const float* __restrict__ h, const float* __restrict__ W,
                             unsigned short* __restrict__ out, int n) {
    __shared__ float sh[64 * 132];
    int t = threadIdx.x;
    int row0 = blockIdx.x * 64;
    int rows = n - row0; if (rows > 64) rows = 64;

    for (int idx4 = t * 4; idx4 < 64 * 128; idx4 += 1024) {
        int r = idx4 >> 7, k = idx4 & 127;
        float4 v;
        if (r < rows) v = *(const float4*)(h + (size_t)(row0 + r) * 128 + k);
        else          v = make_float4(0.f, 0.f, 0.f, 0.f);
        *(float4*)(&sh[r * 132 + k]) = v;
    }
    __syncthreads();

    int f0 = (t & 15) * 8;
    int r0 = (t >> 4) * 4;
    float acc[4][8];
    #pragma unroll
    for (int i = 0; i < 4; ++i)
        #pragma unroll
        for (int c = 0; c < 8; ++c) acc[i][c] = 0.f;

    for (int k0 = 0; k0 < 128; k0 += 4) {
        float a_s[4][4];
        #pragma unroll
        for (int i = 0; i < 4; ++i) {
            float4 v = *(const float4*)(&sh[(r0 + i) * 132 + k0]);
            a_s[i][0] = v.x; a_s[i][1] = v.y; a_s[i][2] = v.z; a_s[i][3] = v.w;
        }
        float w_s[4][8];
        #pragma unroll
        for (int j = 0; j < 4; ++j) {
            float4 w0 = *(const float4*)(W + (size_t)(k0 + j) * 128 + f0);
            float4 w1 = *(const float4*)(W + (size_t)(k0 + j) * 128 + f0 + 4);
            w_s[j][0] = w0.x; w_s[j][1] = w0.y; w_s[j][2] = w0.z; w_s[j][3] = w0.w;
            w_s[j][4] = w1.x; w_s[j][5] = w1.y; w_s[j][6] = w1.z; w_s[j][7] = w1.w;
        }
        #pragma unroll
        for (int j = 0; j < 4; ++j)
            #pragma unroll
            for (int i = 0; i < 4; ++i)
                #pragma unroll
                for (int c = 0; c < 8; ++c)
                    acc[i][c] = fmaf(a_s[i][j], w_s[j][c], acc[i][c]);
    }

    #pragma unroll
    for (int i = 0; i < 4; ++i) {
        if (r0 + i < rows) {
            uint4 o;
            o.x = (unsigned int)f2bf(acc[i][0]) | ((unsigned int)f2bf(acc[i][1]) << 16);
            o.y = (unsigned int)f2bf(acc[i][2]) | ((unsigned int)f2bf(acc[i][3]) << 16);
            o.z = (unsigned int)f2bf(acc[i][4]) | ((unsigned int)f2bf(acc[i][5]) << 16);
            o.w = (unsigned int)f2bf(acc[i][6]) | ((unsigned int)f2bf(acc[i][7]) << 16);
            *(uint4*)(out + (size_t)(row0 + r0 + i) * 128 + f0) = o;
        }
    }
}

// ---------------- aggregation over bf16 table + foldedBN + ReLU ----------------
// Half-wave per gathered row: 32 lanes x uint2 (4 bf16). 2 edges/step, ILP-8.
__launch_bounds__(256)
__global__ void agg_bf16(const uint2* __restrict__ hw, const unsigned short* __restrict__ csr,
                         const int* __restrict__ offs, const int* __restrict__ degi,
                         const float* __restrict__ dinv,
                         const float* __restrict__ sc, const float* __restrict__ shv,
                         float* __restrict__ out, int n) {
    int lane = threadIdx.x & 63;
    int node = blockIdx.x * 4 + (threadIdx.x >> 6);
    if (node >= n) return;
    int fl = lane & 31, half = lane >> 5;
    float di = dinv[node];
    float a0 = 0.f, a1 = 0.f, a2 = 0.f, a3 = 0.f;
    int off = offs[node], cnt = degi[node];

    for (int b0 = 0; b0 < cnt; b0 += 64) {
        int j = b0 + lane;
        int s = 0; float dv = 0.f;
        if (j < cnt) { s = csr[off + j]; dv = dinv[s]; }
        int m = cnt - b0; if (m > 64) m = 64;
        int m16 = (m + 15) & ~15;
        for (int e = 0; e < m16; e += 16) {
            uint2 w[8]; float nn[8];
            #pragma unroll
            for (int u = 0; u < 8; ++u) {
                int jj = e + u * 2 + half;
                int ss = __shfl(s, jj);
                nn[u] = __shfl(dv, jj);        // 0 on pad lanes
                w[u] = hw[(size_t)ss * 32 + fl];
            }
            #pragma unroll
            for (int u = 0; u < 8; ++u) {
                a0 = fmaf(nn[u], bf_lo(w[u].x), a0);
                a1 = fmaf(nn[u], bf_hi(w[u].x), a1);
                a2 = fmaf(nn[u], bf_lo(w[u].y), a2);
                a3 = fmaf(nn[u], bf_hi(w[u].y), a3);
            }
        }
    }
    a0 += __shfl_xor(a0, 32);
    a1 += __shfl_xor(a1, 32);
    a2 += __shfl_xor(a2, 32);
    a3 += __shfl_xor(a3, 32);
    if (half == 0) {
        int f0 = fl * 4;
        uint2 ws = hw[(size_t)node * 32 + fl];
        a0 = (a0 + di * bf_lo(ws.x)) * di;
        a1 = (a1 + di * bf_hi(ws.x)) * di;
        a2 = (a2 + di * bf_lo(ws.y)) * di;
        a3 = (a3 + di * bf_hi(ws.y)) * di;
        float4 o;
        o.x = fmaxf(fmaf(sc[f0],     a0, shv[f0]),     0.f);
        o.y = fmaxf(fmaf(sc[f0 + 1], a1, shv[f0 + 1]), 0.f);
        o.z = fmaxf(fmaf(sc[f0 + 2], a2, shv[f0 + 2]), 0.f);
        o.w = fmaxf(fmaf(sc[f0 + 3], a3, shv[f0 + 3]), 0.f);
        *(float4*)(out + (size_t)node * 128 + f0) = o;
    }
}

// ---------------- segmented mean pool ----------------
__launch_bounds__(128)
__global__ void ligand_kernel(const float* __restrict__ h, const int* __restrict__ gstart,
                              float* __restrict__ lig) {
    int g = blockIdx.x, t = threadIdx.x;
    int s = gstart[g], e = gstart[g + 1];
    float a0 = 0.f, a1 = 0.f, a2 = 0.f, a3 = 0.f;
    int i = s;
    for (; i + 4 <= e; i += 4) {
        a0 += h[(size_t)(i + 0) * 128 + t];
        a1 += h[(size_t)(i + 1) * 128 + t];
        a2 += h[(size_t)(i + 2) * 128 + t];
        a3 += h[(size_t)(i + 3) * 128 + t];
    }
    for (; i < e; ++i) a0 += h[(size_t)i * 128 + t];
    float c = (float)(e - s); if (c < 1.f) c = 1.f;
    lig[(size_t)g * 128 + t] = ((a0 + a1) + (a2 + a3)) / c;
}

// ---------------- pocket MLP ----------------
__global__ void pk_kernel(const float* __restrict__ pf, const float* __restrict__ W1,
                          const float* __restrict__ b1, const float* __restrict__ W2,
                          const float* __restrict__ b2, float* __restrict__ pk) {
    __shared__ float h1[64];
    int t = threadIdx.x;
    float acc = b1[t];
    #pragma unroll
    for (int k = 0; k < 28; ++k) acc = fmaf(pf[k], W1[k * 64 + t], acc);
    h1[t] = fmaxf(acc, 0.f);
    __syncthreads();
    float acc2 = b2[t];
    for (int k = 0; k < 64; ++k) acc2 = fmaf(h1[k], W2[k * 64 + t], acc2);
    pk[t] = acc2;
}

// ---------------- fold bilinear ----------------
__global__ void bilM_kernel(const float* __restrict__ bilW, const float* __restrict__ pk,
                            float* __restrict__ M) {
    __shared__ float spk[64];
    int t = threadIdx.x;
    if (t < 64) spk[t] = pk[t];
    __syncthreads();
    int idx = blockIdx.x * 256 + t;
    if (idx < 64 * 128) {
        const float* wr = bilW + (size_t)idx * 64;
        float acc = 0.f;
        #pragma unroll 8
        for (int j = 0; j < 64; ++j) acc = fmaf(wr[j], spk[j], acc);
        M[idx] = acc;
    }
}

// ---------------- per-graph tail ----------------
__global__ void final_kernel(const float* __restrict__ lig_in, const float* __restrict__ M,
                             const float* __restrict__ bil_b,
                             const float* __restrict__ cW1, const float* __restrict__ cb1,
                             const float* __restrict__ cW2, const float* __restrict__ cb2,
                             float* __restrict__ out) {
    __shared__ float lig[128];
    __shared__ float inter[64];
    __shared__ float hc[32];
    int g = blockIdx.x, t = threadIdx.x;
    lig[t] = lig_in[(size_t)g * 128 + t];
    __syncthreads();
    if (t < 64) {
        float acc = bil_b[t];
        const float* mr = M + (size_t)t * 128;
        #pragma unroll 8
        for (int i = 0; i < 128; ++i) acc = fmaf(lig[i], mr[i], acc);
        inter[t] = acc;
    }
    __syncthreads();
    if (t < 32) {
        float acc = cb1[t];
        #pragma unroll 8
        for (int o = 0; o < 64; ++o) acc = fmaf(inter[o], cW1[o * 32 + t], acc);
        hc[t] = fmaxf(acc, 0.f);
    }
    __syncthreads();
    if (t == 0) {
        float acc = cb2[0];
        #pragma unroll
        for (int j = 0; j < 32; ++j) acc = fmaf(hc[j], cW2[j], acc);
        out[g] = acc;
    }
}

extern "C" void kernel_launch(void* const* d_in, const int* in_sizes, int n_in,
                              void* d_out, int out_size, void* d_ws, size_t ws_size,
                              hipStream_t stream) {
    const float* x        = (const float*)d_in[0];
    const int*   edge     = (const int*)d_in[1];
    const int*   batch    = (const int*)d_in[2];
    const float* pocket   = (const float*)d_in[3];
    const float* conv0_W  = (const float*)d_in[4];
    const float* conv0_b  = (const float*)d_in[5];
    const float* convs_W  = (const float*)d_in[6];
    const float* convs_b  = (const float*)d_in[7];
    const float* bn_gamma = (const float*)d_in[8];
    const float* bn_beta  = (const float*)d_in[9];
    const float* bn_mean  = (const float*)d_in[10];
    const float* bn_var   = (const float*)d_in[11];
    const float* pmlp_W1  = (const float*)d_in[12];
    const float* pmlp_b1  = (const float*)d_in[13];
    const float* pmlp_W2  = (const float*)d_in[14];
    const float* pmlp_b2  = (const float*)d_in[15];
    const float* bil_W    = (const float*)d_in[16];
    const float* bil_b    = (const float*)d_in[17];
    const float* cls_W1   = (const float*)d_in[18];
    const float* cls_b1   = (const float*)d_in[19];
    const float* cls_W2   = (const float*)d_in[20];
    const float* cls_b2   = (const float*)d_in[21];

    const int N = in_sizes[0] / 7;
    const int E = in_sizes[1] / 2;
    const int G = out_size;
    const int* srcA = edge;
    const int* dstA = edge + E;
    const int NB = (N + 255) / 256;

    char* p = (char*)d_ws;
    auto alloc = [&](size_t bytes) -> void* {
        void* r = (void*)p;
        p += (bytes + 255) & ~(size_t)255;
        return r;
    };
    int*   deg      = (int*)alloc((size_t)N * 4);
    int*   cursor   = (int*)alloc((size_t)N * 4);
    int*   offs     = (int*)alloc((size_t)N * 4);
    int*   bsum     = (int*)alloc((size_t)NB * 4);
    float* dinv     = (float*)alloc((size_t)N * 4);
    unsigned short* csr = (unsigned short*)alloc((size_t)E * 2);
    float* xa       = (float*)alloc((size_t)N * 7 * 4);
    unsigned short* bufH = (unsigned short*)alloc((size_t)N * 128 * 2);
    float* bufF     = (float*)alloc((size_t)N * 128 * 4);
    int*   gstart   = (int*)alloc((size_t)(G + 1) * 4);
    float* lig      = (float*)alloc((size_t)G * 128 * 4);
    float* pk       = (float*)alloc(64 * 4);
    float* M        = (float*)alloc(64 * 128 * 4);
    float* sc       = (float*)alloc(384 * 4);
    float* shv      = (float*)alloc(384 * 4);

    init_kernel<<<NB, 256, 0, stream>>>(deg, N);
    count_kernel<<<2048, 256, 0, stream>>>(dstA, deg, E, N);
    blocksum_kernel<<<NB, 256, 0, stream>>>(deg, bsum, N);
    scansum_kernel<<<1, 256, 0, stream>>>(bsum, NB);
    offs_kernel<<<NB, 256, 0, stream>>>(deg, bsum, offs, cursor, dinv, N);
    fill_kernel<<<2048, 256, 0, stream>>>(srcA, dstA, cursor, csr, E, N);
    bounds_kernel<<<NB, 256, 0, stream>>>(batch, gstart, N, G);
    bnfold_kernel<<<1, 384, 0, stream>>>(conv0_b, convs_b, bn_gamma, bn_beta, bn_mean, bn_var,
                                         sc, shv);

    // layer 0
    agg7<<<(N + 3) / 4, 256, 0, stream>>>(x, csr, offs, deg, dinv, xa, N);
    l0_dense<<<((size_t)N * 128 + 255) / 256, 256, 0, stream>>>(xa, conv0_W, sc, shv, bufF, N);

    // layer 1
    gemm128_bf16<<<(N + 63) / 64, 256, 0, stream>>>(bufF, convs_W, bufH, N);
    agg_bf16<<<(N + 3) / 4, 256, 0, stream>>>((const uint2*)bufH, csr, offs, deg, dinv,
                                              sc + 128, shv + 128, bufF, N);
    // layer 2
    gemm128_bf16<<<(N + 63) / 64, 256, 0, stream>>>(bufF, convs_W + 128 * 128, bufH, N);
    agg_bf16<<<(N + 3) / 4, 256, 0, stream>>>((const uint2*)bufH, csr, offs, deg, dinv,
                                              sc + 256, shv + 256, bufF, N);

    ligand_kernel<<<G, 128, 0, stream>>>(bufF, gstart, lig);
    pk_kernel<<<1, 64, 0, stream>>>(pocket, pmlp_W1, pmlp_b1, pmlp_W2, pmlp_b2, pk);
    bilM_kernel<<<32, 256, 0, stream>>>(bil_W, pk, M);
    final_kernel<<<G, 128, 0, stream>>>(lig, M, bil_b, cls_W1, cls_b1, cls_W2, cls_b2,
                                        (float*)d_out);
}